// Round 9
// baseline (320.801 us; speedup 1.0000x reference)
//
#include <hip/hip_runtime.h>

typedef unsigned short u16;
typedef unsigned int u32;
typedef __attribute__((ext_vector_type(4))) float f32x4;
typedef __attribute__((ext_vector_type(8))) short s16x8;
typedef __attribute__((ext_vector_type(4))) u16 u16x4;
typedef __attribute__((ext_vector_type(2))) u32 u32x2;

#define L2E 1.4426950408889634f
#define QSCALE 0.18033688011112042f /* (1/8) * log2(e) */

__device__ __forceinline__ u16 f2bf(float f) {  // RNE
    union { float f; u32 i; } v; v.f = f;
    return (u16)((v.i + 0x7fffu + ((v.i >> 16) & 1u)) >> 16);
}
// pack hi16(a) | hi16(b)<<16 — single v_perm_b32 (bf16 truncation)
__device__ __forceinline__ u32 pack_hi(float a, float b) {
    union { float f; u32 i; } x, y; x.f = a; y.f = b;
    return __builtin_amdgcn_perm(y.i, x.i, 0x07060302u);
}
// bf16 stored in lo/hi half of a u32 -> f32 (1 VALU op each)
__device__ __forceinline__ float bflo(u32 w) {
    union { u32 i; float f; } v; v.i = w << 16; return v.f;
}
__device__ __forceinline__ float bfhi(u32 w) {
    union { u32 i; float f; } v; v.i = w & 0xFFFF0000u; return v.f;
}
// RNE pack of two fp32 -> two bf16 in one instr (lo = a, hi = b).
// Bit-identical to f2bf(a) | f2bf(b)<<16.
__device__ __forceinline__ u32 cvtpk_bf16(float a, float b) {
    u32 d;
    asm("v_cvt_pk_bf16_f32 %0, %1, %2" : "=v"(d) : "v"(a), "v"(b));
    return d;
}
// load 8 fp32 from global, convert to bf16 MFMA fragment in-register
__device__ __forceinline__ s16x8 ldfrag_f32(const float* __restrict__ p) {
    f32x4 x = *(const f32x4*)p;
    f32x4 y = *(const f32x4*)(p + 4);
    union { u32 w[4]; s16x8 v; } u;
    u.w[0] = cvtpk_bf16(x[0], x[1]);
    u.w[1] = cvtpk_bf16(x[2], x[3]);
    u.w[2] = cvtpk_bf16(y[0], y[1]);
    u.w[3] = cvtpk_bf16(y[2], y[3]);
    return u.v;
}

// async global->LDS, 16B per lane; LDS dest = wave-uniform base + lane*16
__device__ __forceinline__ void gl2lds16(const u16* g, u16* l) {
    __builtin_amdgcn_global_load_lds(
        (const __attribute__((address_space(1))) void*)g,
        (__attribute__((address_space(3))) void*)l, 16, 0, 0);
}

// ---------------------------------------------------------------------------
// LDS-free GEMM: C[128x128] = A_f32[128x512] * B_f32^T. Every MFMA fragment
// is 8 contiguous k-elems per lane -> loaded directly from global (L2/L3
// serves the reuse) and converted via v_cvt_pk_bf16_f32 (RNE == old conv).
// No barriers; VMEM latency hidden by wave TLP.
// ---------------------------------------------------------------------------
__device__ __forceinline__ void gemm_f32_nolds(
    const float* __restrict__ A, const float* __restrict__ Bw,
    int m0, int n0, f32x4 acc[4][4])
{
    const int tid = threadIdx.x;
    const int lane = tid & 63, w = tid >> 6;
    const int wm = w >> 1, wn = w & 1;
    const int l16 = lane & 15, quad = lane >> 4;
    const f32x4 vzero = {0.f, 0.f, 0.f, 0.f};
#pragma unroll
    for (int i = 0; i < 4; ++i)
#pragma unroll
        for (int j = 0; j < 4; ++j) acc[i][j] = vzero;

    const float* ap0 = A + (size_t)(m0 + wm * 64 + l16) * 512 + quad * 8;
    const float* bp0 = Bw + (size_t)(n0 + wn * 64 + l16) * 512 + quad * 8;
    for (int kt = 0; kt < 16; ++kt) {
        s16x8 af[4], bfr[4];
#pragma unroll
        for (int mt = 0; mt < 4; ++mt)
            af[mt] = ldfrag_f32(ap0 + (size_t)mt * 16 * 512 + kt * 32);
#pragma unroll
        for (int nt = 0; nt < 4; ++nt)
            bfr[nt] = ldfrag_f32(bp0 + (size_t)nt * 16 * 512 + kt * 32);
#pragma unroll
        for (int mt = 0; mt < 4; ++mt)
#pragma unroll
            for (int nt = 0; nt < 4; ++nt)
                acc[mt][nt] = __builtin_amdgcn_mfma_f32_16x16x32_bf16(
                    af[mt], bfr[nt], acc[mt][nt], 0, 0, 0);
    }
}

// ---------------------------------------------------------------------------
// LDS-free mixed GEMM for out: C[64x128] = A_bf16[64x512] * B_f32^T.
// ---------------------------------------------------------------------------
__device__ __forceinline__ void gemm_m64_nolds(
    const u16* __restrict__ A, const float* __restrict__ Bw,
    int m0, int n0, f32x4 acc[2][4])
{
    const int tid = threadIdx.x;
    const int lane = tid & 63, w = tid >> 6;
    const int wm = w & 1, wn = w >> 1;
    const int l16 = lane & 15, quad = lane >> 4;
    const f32x4 vzero = {0.f, 0.f, 0.f, 0.f};
#pragma unroll
    for (int i = 0; i < 2; ++i)
#pragma unroll
        for (int j = 0; j < 4; ++j) acc[i][j] = vzero;

    const u16* ap0 = A + (size_t)(m0 + wm * 32 + l16) * 512 + quad * 8;
    const float* bp0 = Bw + (size_t)(n0 + wn * 64 + l16) * 512 + quad * 8;
    for (int kt = 0; kt < 16; ++kt) {
        s16x8 af[2], bfr[4];
#pragma unroll
        for (int mt = 0; mt < 2; ++mt)
            af[mt] = *(const s16x8*)(ap0 + (size_t)mt * 16 * 512 + kt * 32);
#pragma unroll
        for (int nt = 0; nt < 4; ++nt)
            bfr[nt] = ldfrag_f32(bp0 + (size_t)nt * 16 * 512 + kt * 32);
#pragma unroll
        for (int mt = 0; mt < 2; ++mt)
#pragma unroll
            for (int nt = 0; nt < 4; ++nt)
                acc[mt][nt] = __builtin_amdgcn_mfma_f32_16x16x32_bf16(
                    af[mt], bfr[nt], acc[mt][nt], 0, 0, 0);
    }
}

// ---------------------------------------------------------------------------
// projlg_kernel: blocks 0..767 = QKV projection straight from fp32 inputs
// (job = bx>>8; no conv kernel, no LDS, no barriers);
// blocks 768..4863 = LGx gate precompute (BW-bound, overlaps the GEMM).
// lg: LGx pre-swizzled gate, flat idx ((((b*128+t16)*32+kt)*64)+lane)*16
//     holds log2(sigmoid(gw*SC+gb)+1e-8) for q=t16*16+(lane&15),
//     k=kt*64+kk*16+(lane>>4)*4+reg.
// ---------------------------------------------------------------------------
__global__ __launch_bounds__(256) void projlg_kernel(
    const float* __restrict__ Qin, const float* __restrict__ KVin,
    const float* __restrict__ Wq, const float* __restrict__ Wk,
    const float* __restrict__ Wv,
    const float* __restrict__ bq, const float* __restrict__ bk,
    const float* __restrict__ bv,
    u16* __restrict__ Qh, u16* __restrict__ Kh, u16* __restrict__ Vt,
    const float* __restrict__ SC, const float* __restrict__ gwp,
    const float* __restrict__ gbp, u16* __restrict__ LGx)
{
    if (blockIdx.x < 768) {
        const int job = blockIdx.x >> 8;
        const int rem = blockIdx.x & 255;
        const int n0 = (rem & 3) * 128, m0 = (rem >> 2) * 128;
        const float* A = (job == 0) ? Qin : KVin;
        const float* W = (job == 0) ? Wq : (job == 1 ? Wk : Wv);
        const float* bias = (job == 0) ? bq : (job == 1 ? bk : bv);
        f32x4 acc[4][4];
        gemm_f32_nolds(A, W, m0, n0, acc);

        const int tid = threadIdx.x, lane = tid & 63, w = tid >> 6;
        const int wm = w >> 1, wn = w & 1, l16 = lane & 15, quad = lane >> 4;
#pragma unroll
        for (int nt = 0; nt < 4; ++nt) {
            int j = n0 + wn * 64 + nt * 16 + l16;
            float bj = bias[j];
            int h = j >> 6, d = j & 63;
#pragma unroll
            for (int mt = 0; mt < 4; ++mt) {
                int trow = m0 + wm * 64 + mt * 16 + quad * 4;
                int bb = trow >> 11, nn = trow & 2047;
                int bh = bb * 8 + h;
                if (job == 2) {
                    u16x4 pv;
#pragma unroll
                    for (int reg = 0; reg < 4; ++reg) pv[reg] = f2bf(acc[mt][nt][reg] + bj);
                    *(u16x4*)&Vt[(size_t)(bh * 64 + d) * 2048 + nn] = pv;
                } else if (job == 0) {
#pragma unroll
                    for (int reg = 0; reg < 4; ++reg)
                        Qh[(size_t)(bh * 2048 + nn + reg) * 64 + d] =
                            f2bf((acc[mt][nt][reg] + bj) * QSCALE);
                } else {
#pragma unroll
                    for (int reg = 0; reg < 4; ++reg)
                        Kh[(size_t)(bh * 2048 + nn + reg) * 64 + d] =
                            f2bf(acc[mt][nt][reg] + bj);
                }
            }
        }
    } else {
        const int flat = (blockIdx.x - 768) * 256 + threadIdx.x;
        const int lane = flat & 63;
        const int kt   = (flat >> 6) & 31;
        const int t16  = (flat >> 11) & 127;
        const int b    = flat >> 18;
        const int l16 = lane & 15, quad = lane >> 4;
        const float tA = -gwp[0] * L2E, tB = -gbp[0] * L2E;
        const float* row = SC + ((size_t)b * 2048 + t16 * 16 + l16) * 2048
                              + kt * 64 + quad * 4;
        __align__(16) u16 tmp[16];
#pragma unroll
        for (int kk = 0; kk < 4; ++kk) {
            f32x4 x = *(const f32x4*)(row + kk * 16);
#pragma unroll
            for (int reg = 0; reg < 4; ++reg) {
                float g = __builtin_amdgcn_rcpf(
                    1.0f + __builtin_amdgcn_exp2f(tA * x[reg] + tB)) + 1e-8f;
                tmp[kk * 4 + reg] = f2bf(__builtin_amdgcn_logf(g));  // log2
            }
        }
        u16* d = LGx + (size_t)flat * 16;
        *(uint4*)d       = *(uint4*)tmp;
        *(uint4*)(d + 8) = *(uint4*)(tmp + 8);
    }
}

// ---------------------------------------------------------------------------
// Attention (R8-verified, 50.2 us, VGPR 88). Block = 256 thr = 4 fat waves
// (32 q each, 2 groups); grid (16,8,4) = 2/CU. KVBLK=128, 16 tiles, one
// barrier each. Each K/V fragment read from LDS once feeds BOTH q-groups.
// K tile [128 key][64 d] + V as two [64 d][64 key] sub-tiles, 128-B rows,
// XOR-swizzled (measured conflict-free). LG folded into QK^T via MFMA C-init;
// P redistributed via permlane32+16_swap.
// ---------------------------------------------------------------------------
__global__ __launch_bounds__(256, 2) void attn_kernel(
    const u16* __restrict__ Qh, const u16* __restrict__ Kh,
    const u16* __restrict__ Vt, const u16* __restrict__ LGx,
    u16* __restrict__ Ob)
{
    __shared__ __align__(16) u16 Ks[2][8192];  // [buf][key(128)][d(64)] swz
    __shared__ __align__(16) u16 Vs[2][8192];  // [buf][half(2)][d(64)][key(64)] swz
    const int tid = threadIdx.x;
    const int w = tid >> 6, lane = tid & 63;
    const int l16 = lane & 15, quad = lane >> 4;
    const int b = blockIdx.z, head = blockIdx.y, qg = blockIdx.x;
    const int bh = b * 8 + head;
    const int q0a = qg * 128 + w * 32, q0b = q0a + 16;
    const int t16a = qg * 8 + w * 2;
    const u16* Qp = Qh + (size_t)bh * 131072;
    const u16* Kp = Kh + (size_t)bh * 131072;
    const u16* Vp = Vt + (size_t)bh * 131072;
    const u16* lgPa = LGx + ((size_t)((b * 128 + t16a) * 32) * 64 + lane) * 16;
    const u16* lgPb = LGx + ((size_t)((b * 128 + t16a + 1) * 32) * 64 + lane) * 16;
    const f32x4 vzero = {0.f, 0.f, 0.f, 0.f};
    const s16x8 ones = {0x3F80, 0x3F80, 0x3F80, 0x3F80,
                        0x3F80, 0x3F80, 0x3F80, 0x3F80};  // bf16 1.0 x8

    // precomputed LDS read bases (u16 units); V formulas == K's
    const int s3 = l16 & 7, s2x = s3 & 3, s4x = s3 & 4;
    const int qsw = (quad ^ s2x) * 8;
    const int rb0 = l16 * 64 + qsw + s4x * 8;          // kc even
    const int rb1 = l16 * 64 + qsw + (4 ^ s4x) * 8;    // kc odd
    const u16* KbL = &Ks[0][0];
    const u16* VbL = &Vs[0][0];

    // staging: waves 0-1 K halves, waves 2-3 V halves; 8 slabs each
    const int sr = lane >> 3, c8 = lane & 7;           // 8 rows x 8 chunks
    const bool isK = (w < 2);
    const int hv = w & 1;
    const u16* sgq = isK
        ? (Kp + (size_t)(hv * 64 + sr) * 64 + (c8 ^ sr) * 8)
        : (Vp + (size_t)sr * 2048 + hv * 64 + (c8 ^ sr) * 8);
    const size_t slabAdv = isK ? 512 : 16384;  // +8 rows (u16)
    const size_t tileAdv = isK ? 8192 : 128;   // next 128-key tile (u16)
    u16* sdb = isK ? &Ks[0][hv * 4096] : &Vs[0][hv * 4096];

    s16x8 qfa0 = *(const s16x8*)&Qp[(size_t)(q0a + l16) * 64 + quad * 8];
    s16x8 qfa1 = *(const s16x8*)&Qp[(size_t)(q0a + l16) * 64 + 32 + quad * 8];
    s16x8 qfb0 = *(const s16x8*)&Qp[(size_t)(q0b + l16) * 64 + quad * 8];
    s16x8 qfb1 = *(const s16x8*)&Qp[(size_t)(q0b + l16) * 64 + 32 + quad * 8];
    f32x4 oA[4], oB[4], laccA = vzero, laccB = vzero;
#pragma unroll
    for (int dn = 0; dn < 4; ++dn) { oA[dn] = vzero; oB[dn] = vzero; }

    // prologue: stage tile 0 into buf 0; LG regs for tile 0 (both groups)
#pragma unroll
    for (int j = 0; j < 8; ++j)
        gl2lds16(sgq + (size_t)j * slabAdv, sdb + j * 512);
    sgq += tileAdv;
    uint4 lga0 = *(const uint4*)lgPa;
    uint4 lga1 = *(const uint4*)(lgPa + 8);
    uint4 lga2 = *(const uint4*)(lgPa + 1024);
    uint4 lga3 = *(const uint4*)(lgPa + 1032);
    uint4 lgb0 = *(const uint4*)lgPb;
    uint4 lgb1 = *(const uint4*)(lgPb + 8);
    uint4 lgb2 = *(const uint4*)(lgPb + 1024);
    uint4 lgb3 = *(const uint4*)(lgPb + 1032);
    lgPa += 2048; lgPb += 2048;

    for (int kt = 0; kt < 16; ++kt) {
        __syncthreads();  // tile[kt&1] staged, previous reads done
        const int bo = (kt & 1) * 8192;
        if (kt < 15) {    // prefetch tile kt+1 into the other buffer
            u16* dd = sdb + (8192 - bo);
#pragma unroll
            for (int j = 0; j < 8; ++j)
                gl2lds16(sgq + (size_t)j * slabAdv, dd + j * 512);
            sgq += tileAdv;
        }
        __builtin_amdgcn_s_setprio(1);
        // S^T = K.Q^T + LG, P = 2^S^T (bf16-truncated, packed), both groups
        u32 PwA8[8][2], PwB8[8][2];
        {
            const u32 wda[8] = {lga0.x, lga0.y, lga0.z, lga0.w,
                                lga1.x, lga1.y, lga1.z, lga1.w};
            const u32 wdb[8] = {lgb0.x, lgb0.y, lgb0.z, lgb0.w,
                                lgb1.x, lgb1.y, lgb1.z, lgb1.w};
#pragma unroll
            for (int kk = 0; kk < 4; ++kk) {
                s16x8 ka = *(const s16x8*)(KbL + bo + rb0 + kk * 1024);
                s16x8 kb = *(const s16x8*)(KbL + bo + rb1 + kk * 1024);
                f32x4 ci;
                ci[0] = bflo(wda[kk * 2]);     ci[1] = bfhi(wda[kk * 2]);
                ci[2] = bflo(wda[kk * 2 + 1]); ci[3] = bfhi(wda[kk * 2 + 1]);
                f32x4 s = __builtin_amdgcn_mfma_f32_16x16x32_bf16(ka, qfa0, ci, 0, 0, 0);
                s = __builtin_amdgcn_mfma_f32_16x16x32_bf16(kb, qfa1, s, 0, 0, 0);
                f32x4 cj;
                cj[0] = bflo(wdb[kk * 2]);     cj[1] = bfhi(wdb[kk * 2]);
                cj[2] = bflo(wdb[kk * 2 + 1]); cj[3] = bfhi(wdb[kk * 2 + 1]);
                f32x4 t = __builtin_amdgcn_mfma_f32_16x16x32_bf16(ka, qfb0, cj, 0, 0, 0);
                t = __builtin_amdgcn_mfma_f32_16x16x32_bf16(kb, qfb1, t, 0, 0, 0);
                PwA8[kk][0] = pack_hi(__builtin_amdgcn_exp2f(s[0]),
                                      __builtin_amdgcn_exp2f(s[1]));
                PwA8[kk][1] = pack_hi(__builtin_amdgcn_exp2f(s[2]),
                                      __builtin_amdgcn_exp2f(s[3]));
                PwB8[kk][0] = pack_hi(__builtin_amdgcn_exp2f(t[0]),
                                      __builtin_amdgcn_exp2f(t[1]));
                PwB8[kk][1] = pack_hi(__builtin_amdgcn_exp2f(t[2]),
                                      __builtin_amdgcn_exp2f(t[3]));
            }
        }
        {
            const u32 wda[8] = {lga2.x, lga2.y, lga2.z, lga2.w,
                                lga3.x, lga3.y, lga3.z, lga3.w};
            const u32 wdb[8] = {lgb2.x, lgb2.y, lgb2.z, lgb2.w,
                                lgb3.x, lgb3.y, lgb3.z, lgb3.w};
#pragma unroll
            for (int kk = 0; kk < 4; ++kk) {
                s16x8 ka = *(const s16x8*)(KbL + bo + rb0 + (4 + kk) * 1024);
                s16x8 kb = *(const s16x8*)(KbL + bo + rb1 + (4 + kk) * 1024);
                f32x4 ci;
                ci[0] = bflo(wda[kk * 2]);     ci[1] = bfhi(wda[kk * 2]);
                ci[2] = bflo(wda[kk * 2 + 1]); ci[3] = bfhi(wda[kk * 2 + 1]);
                f32x4 s = __builtin_amdgcn_mfma_f32_16x16x32_bf16(ka, qfa0, ci, 0, 0, 0);
                s = __builtin_amdgcn_mfma_f32_16x16x32_bf16(kb, qfa1, s, 0, 0, 0);
                f32x4 cj;
                cj[0] = bflo(wdb[kk * 2]);     cj[1] = bfhi(wdb[kk * 2]);
                cj[2] = bflo(wdb[kk * 2 + 1]); cj[3] = bfhi(wdb[kk * 2 + 1]);
                f32x4 t = __builtin_amdgcn_mfma_f32_16x16x32_bf16(ka, qfb0, cj, 0, 0, 0);
                t = __builtin_amdgcn_mfma_f32_16x16x32_bf16(kb, qfb1, t, 0, 0, 0);
                PwA8[4 + kk][0] = pack_hi(__builtin_amdgcn_exp2f(s[0]),
                                          __builtin_amdgcn_exp2f(s[1]));
                PwA8[4 + kk][1] = pack_hi(__builtin_amdgcn_exp2f(s[2]),
                                          __builtin_amdgcn_exp2f(s[3]));
                PwB8[4 + kk][0] = pack_hi(__builtin_amdgcn_exp2f(t[0]),
                                          __builtin_amdgcn_exp2f(t[1]));
                PwB8[4 + kk][1] = pack_hi(__builtin_amdgcn_exp2f(t[2]),
                                          __builtin_amdgcn_exp2f(t[3]));
            }
        }
        if (kt < 15) {    // register-prefetch LG for tile kt+1
            lga0 = *(const uint4*)lgPa;
            lga1 = *(const uint4*)(lgPa + 8);
            lga2 = *(const uint4*)(lgPa + 1024);
            lga3 = *(const uint4*)(lgPa + 1032);
            lgb0 = *(const uint4*)lgPb;
            lgb1 = *(const uint4*)(lgPb + 8);
            lgb2 = *(const uint4*)(lgPb + 1024);
            lgb3 = *(const uint4*)(lgPb + 1032);
            lgPa += 2048; lgPb += 2048;
        }
        // PV + row-sum over 4 key-chunks of 32; V frags read once per chunk
#pragma unroll
        for (int kc = 0; kc < 4; ++kc) {
            union { u32 wrd[4]; s16x8 v; } pa, pb;
#pragma unroll
            for (int i = 0; i < 2; ++i) {
                u32x2 r1 = __builtin_amdgcn_permlane32_swap(
                    PwA8[2 * kc][i], PwA8[2 * kc + 1][i], false, false);
                u32x2 r2 = __builtin_amdgcn_permlane16_swap(
                    r1[0], r1[1], false, false);
                pa.wrd[i]     = r2[0];
                pa.wrd[2 + i] = r2[1];
                u32x2 r3 = __builtin_amdgcn_permlane32_swap(
                    PwB8[2 * kc][i], PwB8[2 * kc + 1][i], false, false);
                u32x2 r4 = __builtin_amdgcn_permlane16_swap(
                    r3[0], r3[1], false, false);
                pb.wrd[i]     = r4[0];
                pb.wrd[2 + i] = r4[1];
            }
            s16x8 pfa = pa.v, pfb = pb.v;
            laccA = __builtin_amdgcn_mfma_f32_16x16x32_bf16(pfa, ones, laccA, 0, 0, 0);
            laccB = __builtin_amdgcn_mfma_f32_16x16x32_bf16(pfb, ones, laccB, 0, 0, 0);
            const int vbb = ((kc & 1) ? rb1 : rb0) + (kc >> 1) * 4096 + bo;
#pragma unroll
            for (int dn = 0; dn < 4; ++dn) {
                s16x8 vf = *(const s16x8*)(VbL + vbb + dn * 1024);
                oA[dn] = __builtin_amdgcn_mfma_f32_16x16x32_bf16(
                    pfa, vf, oA[dn], 0, 0, 0);
                oB[dn] = __builtin_amdgcn_mfma_f32_16x16x32_bf16(
                    pfb, vf, oB[dn], 0, 0, 0);
            }
        }
        __builtin_amdgcn_s_setprio(0);
    }
    // lacc[reg] = sum_k P[q=quad*4+reg][k] — exactly the row this lane stores
#pragma unroll
    for (int reg = 0; reg < 4; ++reg) {
        float invA = __builtin_amdgcn_rcpf(laccA[reg]);
        float invB = __builtin_amdgcn_rcpf(laccB[reg]);
        int trowA = b * 2048 + q0a + quad * 4 + reg;
        int trowB = b * 2048 + q0b + quad * 4 + reg;
#pragma unroll
        for (int dn = 0; dn < 4; ++dn) {
            Ob[(size_t)trowA * 512 + head * 64 + dn * 16 + l16] =
                f2bf(oA[dn][reg] * invA);
            Ob[(size_t)trowB * 512 + head * 64 + dn * 16 + l16] =
                f2bf(oB[dn][reg] * invB);
        }
    }
}

// ---------------------------------------------------------------------------
// Output projection: out = Ob @ Wo^T + bo, fp32 out. LDS-free 64x128 tiles,
// Wo consumed as fp32 directly (cvt_pk in-register). 512 blocks = 2/CU.
// ---------------------------------------------------------------------------
__global__ __launch_bounds__(256) void out_kernel(
    const u16* __restrict__ Ob, const float* __restrict__ Wo,
    const float* __restrict__ bo, float* __restrict__ out)
{
    const int m0 = blockIdx.y * 64, n0 = blockIdx.x * 128;
    f32x4 acc[2][4];
    gemm_m64_nolds(Ob, Wo, m0, n0, acc);
    const int tid = threadIdx.x, lane = tid & 63, w = tid >> 6;
    const int wm = w & 1, wn = w >> 1, l16 = lane & 15, quad = lane >> 4;
#pragma unroll
    for (int nt = 0; nt < 4; ++nt) {
        int j = n0 + wn * 64 + nt * 16 + l16;
        float bj = bo[j];
#pragma unroll
        for (int mt = 0; mt < 2; ++mt) {
            int t = m0 + wm * 32 + mt * 16 + quad * 4;
#pragma unroll
            for (int reg = 0; reg < 4; ++reg)
                out[(size_t)(t + reg) * 512 + j] = acc[mt][nt][reg] + bj;
        }
    }
}

extern "C" void kernel_launch(void* const* d_in, const int* in_sizes, int n_in,
                              void* d_out, int out_size, void* d_ws, size_t ws_size,
                              hipStream_t stream)
{
    const float* Qin  = (const float*)d_in[0];
    const float* KVin = (const float*)d_in[1];
    const float* SC   = (const float*)d_in[2];
    const float* Wq   = (const float*)d_in[3];
    const float* bq   = (const float*)d_in[4];
    const float* Wk   = (const float*)d_in[5];
    const float* bk   = (const float*)d_in[6];
    const float* Wv   = (const float*)d_in[7];
    const float* bv   = (const float*)d_in[8];
    const float* gw   = (const float*)d_in[9];
    const float* gb   = (const float*)d_in[10];
    const float* Wo   = (const float*)d_in[11];
    const float* bo   = (const float*)d_in[12];
    float* out = (float*)d_out;

    // ws layout (u16 units): Qh/Kh/Vt/Ob 4.2M each | LGx 16.8M  (~67 MB)
    u16* Qh   = (u16*)d_ws;
    u16* Kh   = Qh + 4194304;
    u16* Vt   = Kh + 4194304;
    u16* Ob   = Vt + 4194304;
    u16* LGx  = Ob + 4194304;          // 16,777,216 u16 = 32 MiB

    hipLaunchKernelGGL(projlg_kernel, dim3(4864), dim3(256), 0, stream,
                       Qin, KVin, Wq, Wk, Wv, bq, bk, bv, Qh, Kh, Vt,
                       SC, gw, gb, LGx);
    hipLaunchKernelGGL(attn_kernel, dim3(16, 8, 4), dim3(256), 0, stream,
                       Qh, Kh, Vt, LGx, Ob);
    hipLaunchKernelGGL(out_kernel, dim3(4, 128), dim3(256), 0, stream,
                       Ob, Wo, bo, out);
}

// Round 10
// 255.561 us; speedup vs baseline: 1.2553x; 1.2553x over previous
//
#include <hip/hip_runtime.h>

typedef unsigned short u16;
typedef unsigned int u32;
typedef __attribute__((ext_vector_type(4))) float f32x4;
typedef __attribute__((ext_vector_type(8))) short s16x8;
typedef __attribute__((ext_vector_type(4))) u16 u16x4;
typedef __attribute__((ext_vector_type(2))) u32 u32x2;

#define L2E 1.4426950408889634f
#define QSCALE 0.18033688011112042f /* (1/8) * log2(e) */

__device__ __forceinline__ u16 f2bf(float f) {  // RNE
    union { float f; u32 i; } v; v.f = f;
    return (u16)((v.i + 0x7fffu + ((v.i >> 16) & 1u)) >> 16);
}
// pack hi16(a) | hi16(b)<<16 — single v_perm_b32 (bf16 truncation)
__device__ __forceinline__ u32 pack_hi(float a, float b) {
    union { float f; u32 i; } x, y; x.f = a; y.f = b;
    return __builtin_amdgcn_perm(y.i, x.i, 0x07060302u);
}
// bf16 stored in lo/hi half of a u32 -> f32 (1 VALU op each)
__device__ __forceinline__ float bflo(u32 w) {
    union { u32 i; float f; } v; v.i = w << 16; return v.f;
}
__device__ __forceinline__ float bfhi(u32 w) {
    union { u32 i; float f; } v; v.i = w & 0xFFFF0000u; return v.f;
}
// RNE pack of two fp32 -> two bf16 (lo=a, hi=b). Verified bit-identical to
// f2bf pair in R9 (absmax matched exactly).
__device__ __forceinline__ u32 cvtpk_bf16(float a, float b) {
    u32 d;
    asm("v_cvt_pk_bf16_f32 %0, %1, %2" : "=v"(d) : "v"(a), "v"(b));
    return d;
}

// async global->LDS, 16B per lane; LDS dest = wave-uniform base + lane*16
__device__ __forceinline__ void gl2lds16(const u16* g, u16* l) {
    __builtin_amdgcn_global_load_lds(
        (const __attribute__((address_space(1))) void*)g,
        (__attribute__((address_space(3))) void*)l, 16, 0, 0);
}
__device__ __forceinline__ void gl2lds16f(const float* g, float* l) {
    __builtin_amdgcn_global_load_lds(
        (const __attribute__((address_space(1))) void*)g,
        (__attribute__((address_space(3))) void*)l, 16, 0, 0);
}

// fp32x8 LDS fragment -> bf16 MFMA fragment (R9-verified cvt order)
__device__ __forceinline__ s16x8 frag_from_f32(const float* base, int c0, int c1) {
    f32x4 lo = *(const f32x4*)(base + c0);
    f32x4 hi = *(const f32x4*)(base + c1);
    union { u32 wd[4]; s16x8 v; } u;
    u.wd[0] = cvtpk_bf16(lo[0], lo[1]);
    u.wd[1] = cvtpk_bf16(lo[2], lo[3]);
    u.wd[2] = cvtpk_bf16(hi[0], hi[1]);
    u.wd[3] = cvtpk_bf16(hi[2], hi[3]);
    return u.v;
}

// ---------------------------------------------------------------------------
// fp32-input LDS-staged GEMM: C[128x128] = A_f32[128x512] * B_f32^T.
// LDS: [2][128 rows][32 fp32] per operand (64 KB total), double-buffered,
// global_load_lds staging with the proven c8^sr 16B-chunk XOR swizzle
// (read pattern isomorphic to the measured conflict-free bf16 path).
// Fragments converted fp32->bf16 in-register (RNE, bit-identical to conv).
// ---------------------------------------------------------------------------
__device__ __forceinline__ void gemm_core_f32(
    const float* __restrict__ A, const float* __restrict__ Bw,
    int m0, int n0, float* AsF, float* BsF, f32x4 acc[4][4])
{
    const int tid = threadIdx.x;
    const int lane = tid & 63, w = tid >> 6;
    const int wm = w >> 1, wn = w & 1;
    const int l16 = lane & 15, quad = lane >> 4;
    const int sr = lane >> 3, c8 = lane & 7;
    const int sch = ((c8 ^ sr) * 4);          // swizzled fp32 col offset
    const f32x4 vzero = {0.f, 0.f, 0.f, 0.f};
#pragma unroll
    for (int i = 0; i < 4; ++i)
#pragma unroll
        for (int j = 0; j < 4; ++j) acc[i][j] = vzero;

    // prologue: stage kt=0 into buffer 0 (each wave: 4 slabs of 8 rows)
#pragma unroll
    for (int jj = 0; jj < 4; ++jj) {
        int row = w * 32 + jj * 8 + sr;
        gl2lds16f(&A[(size_t)(m0 + row) * 512 + sch], &AsF[(w * 32 + jj * 8) * 32]);
        gl2lds16f(&Bw[(size_t)(n0 + row) * 512 + sch], &BsF[(w * 32 + jj * 8) * 32]);
    }
    const int s = l16 & 7;
    const int ca0 = ((2 * quad) ^ s) * 4, ca1 = ((2 * quad + 1) ^ s) * 4;
    for (int kt = 0; kt < 16; ++kt) {
        __syncthreads();
        const int cur = (kt & 1) * 4096;      // floats
        if (kt < 15) {
            const int nxt = 4096 - cur;
#pragma unroll
            for (int jj = 0; jj < 4; ++jj) {
                int row = w * 32 + jj * 8 + sr;
                gl2lds16f(&A[(size_t)(m0 + row) * 512 + (kt + 1) * 32 + sch],
                          &AsF[nxt + (w * 32 + jj * 8) * 32]);
                gl2lds16f(&Bw[(size_t)(n0 + row) * 512 + (kt + 1) * 32 + sch],
                          &BsF[nxt + (w * 32 + jj * 8) * 32]);
            }
        }
        s16x8 af[4], bfr[4];
#pragma unroll
        for (int mt = 0; mt < 4; ++mt)
            af[mt] = frag_from_f32(AsF + cur + (wm * 64 + mt * 16 + l16) * 32, ca0, ca1);
#pragma unroll
        for (int nt = 0; nt < 4; ++nt)
            bfr[nt] = frag_from_f32(BsF + cur + (wn * 64 + nt * 16 + l16) * 32, ca0, ca1);
#pragma unroll
        for (int mt = 0; mt < 4; ++mt)
#pragma unroll
            for (int nt = 0; nt < 4; ++nt)
                acc[mt][nt] = __builtin_amdgcn_mfma_f32_16x16x32_bf16(
                    af[mt], bfr[nt], acc[mt][nt], 0, 0, 0);
    }
}

// ---------------------------------------------------------------------------
// Mixed M=64 GEMM for out: C[64x128] = A_bf16[64x512] * B_f32^T.
// A staged bf16 (R8-exact), B staged fp32 with the swizzle above.
// ---------------------------------------------------------------------------
__device__ __forceinline__ void gemm_m64_f32(
    const u16* __restrict__ A, const float* __restrict__ Bw,
    int m0, int n0, u16* As, float* BsF, f32x4 acc[2][4])
{
    const int tid = threadIdx.x;
    const int lane = tid & 63, w = tid >> 6;
    const int wm = w & 1, wn = w >> 1;
    const int l16 = lane & 15, quad = lane >> 4;
    const int srowA = (lane >> 2), schA = (lane & 3) * 8;   // bf16 A staging
    const int sr = lane >> 3, c8 = lane & 7;
    const int sch = ((c8 ^ sr) * 4);                        // fp32 B staging
    const f32x4 vzero = {0.f, 0.f, 0.f, 0.f};
#pragma unroll
    for (int i = 0; i < 2; ++i)
#pragma unroll
        for (int j = 0; j < 4; ++j) acc[i][j] = vzero;

    gl2lds16(&A[(size_t)(m0 + w * 16 + srowA) * 512 + schA], &As[w * 512]);
#pragma unroll
    for (int jj = 0; jj < 4; ++jj) {
        int row = w * 32 + jj * 8 + sr;
        gl2lds16f(&Bw[(size_t)(n0 + row) * 512 + sch], &BsF[(w * 32 + jj * 8) * 32]);
    }
    const int s = l16 & 7;
    const int ca0 = ((2 * quad) ^ s) * 4, ca1 = ((2 * quad + 1) ^ s) * 4;
    for (int kt = 0; kt < 16; ++kt) {
        __syncthreads();
        const int curA = (kt & 1) * 2048, curB = (kt & 1) * 4096;
        if (kt < 15) {
            const int nxtA = 2048 - curA, nxtB = 4096 - curB;
            gl2lds16(&A[(size_t)(m0 + w * 16 + srowA) * 512 + (kt + 1) * 32 + schA],
                     &As[nxtA + w * 512]);
#pragma unroll
            for (int jj = 0; jj < 4; ++jj) {
                int row = w * 32 + jj * 8 + sr;
                gl2lds16f(&Bw[(size_t)(n0 + row) * 512 + (kt + 1) * 32 + sch],
                          &BsF[nxtB + (w * 32 + jj * 8) * 32]);
            }
        }
        s16x8 af[2], bfr[4];
#pragma unroll
        for (int mt = 0; mt < 2; ++mt)
            af[mt] = *(const s16x8*)&As[curA + (wm * 32 + mt * 16 + l16) * 32 + quad * 8];
#pragma unroll
        for (int nt = 0; nt < 4; ++nt)
            bfr[nt] = frag_from_f32(BsF + curB + (wn * 64 + nt * 16 + l16) * 32, ca0, ca1);
#pragma unroll
        for (int mt = 0; mt < 2; ++mt)
#pragma unroll
            for (int nt = 0; nt < 4; ++nt)
                acc[mt][nt] = __builtin_amdgcn_mfma_f32_16x16x32_bf16(
                    af[mt], bfr[nt], acc[mt][nt], 0, 0, 0);
    }
}

// ---------------------------------------------------------------------------
// projlg_kernel: blocks 0..767 = QKV projection straight from fp32 inputs
// (LDS-staged fp32 GEMM — no conv kernel needed);
// blocks 768..4863 = LGx gate precompute (BW-bound, overlaps the GEMM).
// lg: LGx pre-swizzled gate, flat idx ((((b*128+t16)*32+kt)*64)+lane)*16
//     holds log2(sigmoid(gw*SC+gb)+1e-8) for q=t16*16+(lane&15),
//     k=kt*64+kk*16+(lane>>4)*4+reg.
// ---------------------------------------------------------------------------
__global__ __launch_bounds__(256) void projlg_kernel(
    const float* __restrict__ Qin, const float* __restrict__ KVin,
    const float* __restrict__ Wq, const float* __restrict__ Wk,
    const float* __restrict__ Wv,
    const float* __restrict__ bq, const float* __restrict__ bk,
    const float* __restrict__ bv,
    u16* __restrict__ Qh, u16* __restrict__ Kh, u16* __restrict__ Vt,
    const float* __restrict__ SC, const float* __restrict__ gwp,
    const float* __restrict__ gbp, u16* __restrict__ LGx)
{
    __shared__ __align__(16) float AsF[2 * 4096];   // 32 KB
    __shared__ __align__(16) float BsF[2 * 4096];   // 32 KB
    if (blockIdx.x < 768) {
        const int job = blockIdx.x >> 8;
        const int rem = blockIdx.x & 255;
        const int n0 = (rem & 3) * 128, m0 = (rem >> 2) * 128;
        const float* A = (job == 0) ? Qin : KVin;
        const float* W = (job == 0) ? Wq : (job == 1 ? Wk : Wv);
        const float* bias = (job == 0) ? bq : (job == 1 ? bk : bv);
        f32x4 acc[4][4];
        gemm_core_f32(A, W, m0, n0, AsF, BsF, acc);

        const int tid = threadIdx.x, lane = tid & 63, w = tid >> 6;
        const int wm = w >> 1, wn = w & 1, l16 = lane & 15, quad = lane >> 4;
#pragma unroll
        for (int nt = 0; nt < 4; ++nt) {
            int j = n0 + wn * 64 + nt * 16 + l16;
            float bj = bias[j];
            int h = j >> 6, d = j & 63;
#pragma unroll
            for (int mt = 0; mt < 4; ++mt) {
                int trow = m0 + wm * 64 + mt * 16 + quad * 4;
                int bb = trow >> 11, nn = trow & 2047;
                int bh = bb * 8 + h;
                if (job == 2) {
                    u16x4 pv;
#pragma unroll
                    for (int reg = 0; reg < 4; ++reg) pv[reg] = f2bf(acc[mt][nt][reg] + bj);
                    *(u16x4*)&Vt[(size_t)(bh * 64 + d) * 2048 + nn] = pv;
                } else if (job == 0) {
#pragma unroll
                    for (int reg = 0; reg < 4; ++reg)
                        Qh[(size_t)(bh * 2048 + nn + reg) * 64 + d] =
                            f2bf((acc[mt][nt][reg] + bj) * QSCALE);
                } else {
#pragma unroll
                    for (int reg = 0; reg < 4; ++reg)
                        Kh[(size_t)(bh * 2048 + nn + reg) * 64 + d] =
                            f2bf(acc[mt][nt][reg] + bj);
                }
            }
        }
    } else {
        const int flat = (blockIdx.x - 768) * 256 + threadIdx.x;
        const int lane = flat & 63;
        const int kt   = (flat >> 6) & 31;
        const int t16  = (flat >> 11) & 127;
        const int b    = flat >> 18;
        const int l16 = lane & 15, quad = lane >> 4;
        const float tA = -gwp[0] * L2E, tB = -gbp[0] * L2E;
        const float* row = SC + ((size_t)b * 2048 + t16 * 16 + l16) * 2048
                              + kt * 64 + quad * 4;
        __align__(16) u16 tmp[16];
#pragma unroll
        for (int kk = 0; kk < 4; ++kk) {
            f32x4 x = *(const f32x4*)(row + kk * 16);
#pragma unroll
            for (int reg = 0; reg < 4; ++reg) {
                float g = __builtin_amdgcn_rcpf(
                    1.0f + __builtin_amdgcn_exp2f(tA * x[reg] + tB)) + 1e-8f;
                tmp[kk * 4 + reg] = f2bf(__builtin_amdgcn_logf(g));  // log2
            }
        }
        u16* d = LGx + (size_t)flat * 16;
        *(uint4*)d       = *(uint4*)tmp;
        *(uint4*)(d + 8) = *(uint4*)(tmp + 8);
    }
}

// ---------------------------------------------------------------------------
// Attention (R8-verified, 50.2 us, VGPR 88). Block = 256 thr = 4 fat waves
// (32 q each, 2 groups); grid (16,8,4) = 2/CU. KVBLK=128, 16 tiles, one
// barrier each. Each K/V fragment read from LDS once feeds BOTH q-groups.
// K tile [128 key][64 d] + V as two [64 d][64 key] sub-tiles, 128-B rows,
// XOR-swizzled (measured conflict-free). LG folded into QK^T via MFMA C-init;
// P redistributed via permlane32+16_swap.
// ---------------------------------------------------------------------------
__global__ __launch_bounds__(256, 2) void attn_kernel(
    const u16* __restrict__ Qh, const u16* __restrict__ Kh,
    const u16* __restrict__ Vt, const u16* __restrict__ LGx,
    u16* __restrict__ Ob)
{
    __shared__ __align__(16) u16 Ks[2][8192];  // [buf][key(128)][d(64)] swz
    __shared__ __align__(16) u16 Vs[2][8192];  // [buf][half(2)][d(64)][key(64)] swz
    const int tid = threadIdx.x;
    const int w = tid >> 6, lane = tid & 63;
    const int l16 = lane & 15, quad = lane >> 4;
    const int b = blockIdx.z, head = blockIdx.y, qg = blockIdx.x;
    const int bh = b * 8 + head;
    const int q0a = qg * 128 + w * 32, q0b = q0a + 16;
    const int t16a = qg * 8 + w * 2;
    const u16* Qp = Qh + (size_t)bh * 131072;
    const u16* Kp = Kh + (size_t)bh * 131072;
    const u16* Vp = Vt + (size_t)bh * 131072;
    const u16* lgPa = LGx + ((size_t)((b * 128 + t16a) * 32) * 64 + lane) * 16;
    const u16* lgPb = LGx + ((size_t)((b * 128 + t16a + 1) * 32) * 64 + lane) * 16;
    const f32x4 vzero = {0.f, 0.f, 0.f, 0.f};
    const s16x8 ones = {0x3F80, 0x3F80, 0x3F80, 0x3F80,
                        0x3F80, 0x3F80, 0x3F80, 0x3F80};  // bf16 1.0 x8

    // precomputed LDS read bases (u16 units); V formulas == K's
    const int s3 = l16 & 7, s2x = s3 & 3, s4x = s3 & 4;
    const int qsw = (quad ^ s2x) * 8;
    const int rb0 = l16 * 64 + qsw + s4x * 8;          // kc even
    const int rb1 = l16 * 64 + qsw + (4 ^ s4x) * 8;    // kc odd
    const u16* KbL = &Ks[0][0];
    const u16* VbL = &Vs[0][0];

    // staging: waves 0-1 K halves, waves 2-3 V halves; 8 slabs each
    const int sr = lane >> 3, c8 = lane & 7;           // 8 rows x 8 chunks
    const bool isK = (w < 2);
    const int hv = w & 1;
    const u16* sgq = isK
        ? (Kp + (size_t)(hv * 64 + sr) * 64 + (c8 ^ sr) * 8)
        : (Vp + (size_t)sr * 2048 + hv * 64 + (c8 ^ sr) * 8);
    const size_t slabAdv = isK ? 512 : 16384;  // +8 rows (u16)
    const size_t tileAdv = isK ? 8192 : 128;   // next 128-key tile (u16)
    u16* sdb = isK ? &Ks[0][hv * 4096] : &Vs[0][hv * 4096];

    s16x8 qfa0 = *(const s16x8*)&Qp[(size_t)(q0a + l16) * 64 + quad * 8];
    s16x8 qfa1 = *(const s16x8*)&Qp[(size_t)(q0a + l16) * 64 + 32 + quad * 8];
    s16x8 qfb0 = *(const s16x8*)&Qp[(size_t)(q0b + l16) * 64 + quad * 8];
    s16x8 qfb1 = *(const s16x8*)&Qp[(size_t)(q0b + l16) * 64 + 32 + quad * 8];
    f32x4 oA[4], oB[4], laccA = vzero, laccB = vzero;
#pragma unroll
    for (int dn = 0; dn < 4; ++dn) { oA[dn] = vzero; oB[dn] = vzero; }

    // prologue: stage tile 0 into buf 0; LG regs for tile 0 (both groups)
#pragma unroll
    for (int j = 0; j < 8; ++j)
        gl2lds16(sgq + (size_t)j * slabAdv, sdb + j * 512);
    sgq += tileAdv;
    uint4 lga0 = *(const uint4*)lgPa;
    uint4 lga1 = *(const uint4*)(lgPa + 8);
    uint4 lga2 = *(const uint4*)(lgPa + 1024);
    uint4 lga3 = *(const uint4*)(lgPa + 1032);
    uint4 lgb0 = *(const uint4*)lgPb;
    uint4 lgb1 = *(const uint4*)(lgPb + 8);
    uint4 lgb2 = *(const uint4*)(lgPb + 1024);
    uint4 lgb3 = *(const uint4*)(lgPb + 1032);
    lgPa += 2048; lgPb += 2048;

    for (int kt = 0; kt < 16; ++kt) {
        __syncthreads();  // tile[kt&1] staged, previous reads done
        const int bo = (kt & 1) * 8192;
        if (kt < 15) {    // prefetch tile kt+1 into the other buffer
            u16* dd = sdb + (8192 - bo);
#pragma unroll
            for (int j = 0; j < 8; ++j)
                gl2lds16(sgq + (size_t)j * slabAdv, dd + j * 512);
            sgq += tileAdv;
        }
        __builtin_amdgcn_s_setprio(1);
        // S^T = K.Q^T + LG, P = 2^S^T (bf16-truncated, packed), both groups
        u32 PwA8[8][2], PwB8[8][2];
        {
            const u32 wda[8] = {lga0.x, lga0.y, lga0.z, lga0.w,
                                lga1.x, lga1.y, lga1.z, lga1.w};
            const u32 wdb[8] = {lgb0.x, lgb0.y, lgb0.z, lgb0.w,
                                lgb1.x, lgb1.y, lgb1.z, lgb1.w};
#pragma unroll
            for (int kk = 0; kk < 4; ++kk) {
                s16x8 ka = *(const s16x8*)(KbL + bo + rb0 + kk * 1024);
                s16x8 kb = *(const s16x8*)(KbL + bo + rb1 + kk * 1024);
                f32x4 ci;
                ci[0] = bflo(wda[kk * 2]);     ci[1] = bfhi(wda[kk * 2]);
                ci[2] = bflo(wda[kk * 2 + 1]); ci[3] = bfhi(wda[kk * 2 + 1]);
                f32x4 s = __builtin_amdgcn_mfma_f32_16x16x32_bf16(ka, qfa0, ci, 0, 0, 0);
                s = __builtin_amdgcn_mfma_f32_16x16x32_bf16(kb, qfa1, s, 0, 0, 0);
                f32x4 cj;
                cj[0] = bflo(wdb[kk * 2]);     cj[1] = bfhi(wdb[kk * 2]);
                cj[2] = bflo(wdb[kk * 2 + 1]); cj[3] = bfhi(wdb[kk * 2 + 1]);
                f32x4 t = __builtin_amdgcn_mfma_f32_16x16x32_bf16(ka, qfb0, cj, 0, 0, 0);
                t = __builtin_amdgcn_mfma_f32_16x16x32_bf16(kb, qfb1, t, 0, 0, 0);
                PwA8[kk][0] = pack_hi(__builtin_amdgcn_exp2f(s[0]),
                                      __builtin_amdgcn_exp2f(s[1]));
                PwA8[kk][1] = pack_hi(__builtin_amdgcn_exp2f(s[2]),
                                      __builtin_amdgcn_exp2f(s[3]));
                PwB8[kk][0] = pack_hi(__builtin_amdgcn_exp2f(t[0]),
                                      __builtin_amdgcn_exp2f(t[1]));
                PwB8[kk][1] = pack_hi(__builtin_amdgcn_exp2f(t[2]),
                                      __builtin_amdgcn_exp2f(t[3]));
            }
        }
        {
            const u32 wda[8] = {lga2.x, lga2.y, lga2.z, lga2.w,
                                lga3.x, lga3.y, lga3.z, lga3.w};
            const u32 wdb[8] = {lgb2.x, lgb2.y, lgb2.z, lgb2.w,
                                lgb3.x, lgb3.y, lgb3.z, lgb3.w};
#pragma unroll
            for (int kk = 0; kk < 4; ++kk) {
                s16x8 ka = *(const s16x8*)(KbL + bo + rb0 + (4 + kk) * 1024);
                s16x8 kb = *(const s16x8*)(KbL + bo + rb1 + (4 + kk) * 1024);
                f32x4 ci;
                ci[0] = bflo(wda[kk * 2]);     ci[1] = bfhi(wda[kk * 2]);
                ci[2] = bflo(wda[kk * 2 + 1]); ci[3] = bfhi(wda[kk * 2 + 1]);
                f32x4 s = __builtin_amdgcn_mfma_f32_16x16x32_bf16(ka, qfa0, ci, 0, 0, 0);
                s = __builtin_amdgcn_mfma_f32_16x16x32_bf16(kb, qfa1, s, 0, 0, 0);
                f32x4 cj;
                cj[0] = bflo(wdb[kk * 2]);     cj[1] = bfhi(wdb[kk * 2]);
                cj[2] = bflo(wdb[kk * 2 + 1]); cj[3] = bfhi(wdb[kk * 2 + 1]);
                f32x4 t = __builtin_amdgcn_mfma_f32_16x16x32_bf16(ka, qfb0, cj, 0, 0, 0);
                t = __builtin_amdgcn_mfma_f32_16x16x32_bf16(kb, qfb1, t, 0, 0, 0);
                PwA8[4 + kk][0] = pack_hi(__builtin_amdgcn_exp2f(s[0]),
                                          __builtin_amdgcn_exp2f(s[1]));
                PwA8[4 + kk][1] = pack_hi(__builtin_amdgcn_exp2f(s[2]),
                                          __builtin_amdgcn_exp2f(s[3]));
                PwB8[4 + kk][0] = pack_hi(__builtin_amdgcn_exp2f(t[0]),
                                          __builtin_amdgcn_exp2f(t[1]));
                PwB8[4 + kk][1] = pack_hi(__builtin_amdgcn_exp2f(t[2]),
                                          __builtin_amdgcn_exp2f(t[3]));
            }
        }
        if (kt < 15) {    // register-prefetch LG for tile kt+1
            lga0 = *(const uint4*)lgPa;
            lga1 = *(const uint4*)(lgPa + 8);
            lga2 = *(const uint4*)(lgPa + 1024);
            lga3 = *(const uint4*)(lgPa + 1032);
            lgb0 = *(const uint4*)lgPb;
            lgb1 = *(const uint4*)(lgPb + 8);
            lgb2 = *(const uint4*)(lgPb + 1024);
            lgb3 = *(const uint4*)(lgPb + 1032);
            lgPa += 2048; lgPb += 2048;
        }
        // PV + row-sum over 4 key-chunks of 32; V frags read once per chunk
#pragma unroll
        for (int kc = 0; kc < 4; ++kc) {
            union { u32 wrd[4]; s16x8 v; } pa, pb;
#pragma unroll
            for (int i = 0; i < 2; ++i) {
                u32x2 r1 = __builtin_amdgcn_permlane32_swap(
                    PwA8[2 * kc][i], PwA8[2 * kc + 1][i], false, false);
                u32x2 r2 = __builtin_amdgcn_permlane16_swap(
                    r1[0], r1[1], false, false);
                pa.wrd[i]     = r2[0];
                pa.wrd[2 + i] = r2[1];
                u32x2 r3 = __builtin_amdgcn_permlane32_swap(
                    PwB8[2 * kc][i], PwB8[2 * kc + 1][i], false, false);
                u32x2 r4 = __builtin_amdgcn_permlane16_swap(
                    r3[0], r3[1], false, false);
                pb.wrd[i]     = r4[0];
                pb.wrd[2 + i] = r4[1];
            }
            s16x8 pfa = pa.v, pfb = pb.v;
            laccA = __builtin_amdgcn_mfma_f32_16x16x32_bf16(pfa, ones, laccA, 0, 0, 0);
            laccB = __builtin_amdgcn_mfma_f32_16x16x32_bf16(pfb, ones, laccB, 0, 0, 0);
            const int vbb = ((kc & 1) ? rb1 : rb0) + (kc >> 1) * 4096 + bo;
#pragma unroll
            for (int dn = 0; dn < 4; ++dn) {
                s16x8 vf = *(const s16x8*)(VbL + vbb + dn * 1024);
                oA[dn] = __builtin_amdgcn_mfma_f32_16x16x32_bf16(
                    pfa, vf, oA[dn], 0, 0, 0);
                oB[dn] = __builtin_amdgcn_mfma_f32_16x16x32_bf16(
                    pfb, vf, oB[dn], 0, 0, 0);
            }
        }
        __builtin_amdgcn_s_setprio(0);
    }
    // lacc[reg] = sum_k P[q=quad*4+reg][k] — exactly the row this lane stores
#pragma unroll
    for (int reg = 0; reg < 4; ++reg) {
        float invA = __builtin_amdgcn_rcpf(laccA[reg]);
        float invB = __builtin_amdgcn_rcpf(laccB[reg]);
        int trowA = b * 2048 + q0a + quad * 4 + reg;
        int trowB = b * 2048 + q0b + quad * 4 + reg;
#pragma unroll
        for (int dn = 0; dn < 4; ++dn) {
            Ob[(size_t)trowA * 512 + head * 64 + dn * 16 + l16] =
                f2bf(oA[dn][reg] * invA);
            Ob[(size_t)trowB * 512 + head * 64 + dn * 16 + l16] =
                f2bf(oB[dn][reg] * invB);
        }
    }
}

// ---------------------------------------------------------------------------
// Output projection: out = Ob @ Wo^T + bo, fp32 out. 64x128 tiles, Wo fp32
// staged through LDS (cvt in-register). 512 blocks = 2/CU.
// ---------------------------------------------------------------------------
__global__ __launch_bounds__(256) void out_kernel(
    const u16* __restrict__ Ob, const float* __restrict__ Wo,
    const float* __restrict__ bo, float* __restrict__ out)
{
    __shared__ __align__(16) u16 As[2 * 2048];      // 8 KB
    __shared__ __align__(16) float BsF[2 * 4096];   // 32 KB
    const int m0 = blockIdx.y * 64, n0 = blockIdx.x * 128;
    f32x4 acc[2][4];
    gemm_m64_f32(Ob, Wo, m0, n0, As, BsF, acc);
    const int tid = threadIdx.x, lane = tid & 63, w = tid >> 6;
    const int wm = w & 1, wn = w >> 1, l16 = lane & 15, quad = lane >> 4;
#pragma unroll
    for (int nt = 0; nt < 4; ++nt) {
        int j = n0 + wn * 64 + nt * 16 + l16;
        float bj = bo[j];
#pragma unroll
        for (int mt = 0; mt < 2; ++mt) {
            int t = m0 + wm * 32 + mt * 16 + quad * 4;
#pragma unroll
            for (int reg = 0; reg < 4; ++reg)
                out[(size_t)(t + reg) * 512 + j] = acc[mt][nt][reg] + bj;
        }
    }
}

extern "C" void kernel_launch(void* const* d_in, const int* in_sizes, int n_in,
                              void* d_out, int out_size, void* d_ws, size_t ws_size,
                              hipStream_t stream)
{
    const float* Qin  = (const float*)d_in[0];
    const float* KVin = (const float*)d_in[1];
    const float* SC   = (const float*)d_in[2];
    const float* Wq   = (const float*)d_in[3];
    const float* bq   = (const float*)d_in[4];
    const float* Wk   = (const float*)d_in[5];
    const float* bk   = (const float*)d_in[6];
    const float* Wv   = (const float*)d_in[7];
    const float* bv   = (const float*)d_in[8];
    const float* gw   = (const float*)d_in[9];
    const float* gb   = (const float*)d_in[10];
    const float* Wo   = (const float*)d_in[11];
    const float* bo   = (const float*)d_in[12];
    float* out = (float*)d_out;

    // ws layout (u16 units): Qh/Kh/Vt/Ob 4.2M each | LGx 16.8M  (~67 MB)
    u16* Qh   = (u16*)d_ws;
    u16* Kh   = Qh + 4194304;
    u16* Vt   = Kh + 4194304;
    u16* Ob   = Vt + 4194304;
    u16* LGx  = Ob + 4194304;          // 16,777,216 u16 = 32 MiB

    hipLaunchKernelGGL(projlg_kernel, dim3(4864), dim3(256), 0, stream,
                       Qin, KVin, Wq, Wk, Wv, bq, bk, bv, Qh, Kh, Vt,
                       SC, gw, gb, LGx);
    hipLaunchKernelGGL(attn_kernel, dim3(16, 8, 4), dim3(256), 0, stream,
                       Qh, Kh, Vt, LGx, Ob);
    hipLaunchKernelGGL(out_kernel, dim3(4, 128), dim3(256), 0, stream,
                       Ob, Wo, bo, out);
}